// Round 1
// baseline (314.397 us; speedup 1.0000x reference)
//
#include <hip/hip_runtime.h>
#include <math.h>

#define B_N 8
#define IN_N 8
#define J_N 8
#define S_N 187
#define F_N 64
#define O_N 64
#define C_N 67
#define KS_N 15
#define SF_N (S_N * F_N)   // 11968
#define E_N 256
#define SQRT_SF 0.85467470f  // sqrt(187/256)

// ---------------- wave helpers (wave = 64) ----------------
__device__ __forceinline__ float wave_sum(float v) {
#pragma unroll
  for (int off = 32; off > 0; off >>= 1) v += __shfl_down(v, off, 64);
  return __shfl(v, 0, 64);
}
__device__ __forceinline__ float wave_max(float v) {
#pragma unroll
  for (int off = 32; off > 0; off >>= 1) v = fmaxf(v, __shfl_down(v, off, 64));
  return __shfl(v, 0, 64);
}

__device__ __forceinline__ float bspline(float d) {
  float t2 = fmaxf(2.f - d, 0.f);
  float t1 = fmaxf(1.f - d, 0.f);
  return t2 * t2 * t2 * (1.f / 6.f) - t1 * t1 * t1 * (4.f / 6.f);
}

// ---------------- 1. global max |x| ----------------
__global__ void k_maxabs(const float* __restrict__ x, unsigned int* __restrict__ out, int n) {
  int tid = blockIdx.x * blockDim.x + threadIdx.x;
  float m = 0.f;
  for (int i = tid; i < n; i += gridDim.x * blockDim.x) m = fmaxf(m, fabsf(x[i]));
  m = wave_max(m);
  if ((threadIdx.x & 63) == 0) atomicMax(out, __float_as_uint(m));
}

// ---------------- 2. energies -> mask, g = mult*mask ----------------
// grid = B*IN blocks, 256 threads
__global__ void k_energy(const float* __restrict__ x_in, const float* __restrict__ sw,
                         const float* __restrict__ tau, const float* __restrict__ temp,
                         const float* __restrict__ omiga,
                         const unsigned int* __restrict__ maxbits,
                         float* __restrict__ maskv, float* __restrict__ g) {
  int b = blockIdx.x >> 3, i = blockIdx.x & 7;
  __shared__ float wl[J_N * C_N];
  __shared__ float aom[J_N];
  __shared__ float red[4 * J_N];
  for (int idx = threadIdx.x; idx < J_N * C_N; idx += 256) wl[idx] = sw[i * J_N * C_N + idx];
  if (threadIdx.x < J_N) aom[threadIdx.x] = fabsf(omiga[i * J_N + threadIdx.x]);
  __syncthreads();
  float maxv = __uint_as_float(*maxbits) + 1e-8f;
  float inv = 0.95f / maxv;
  float acc[J_N] = {0, 0, 0, 0, 0, 0, 0, 0};
  const float* xb = x_in + (b * IN_N + i) * SF_N;
  for (int idx = threadIdx.x; idx < SF_N; idx += 256) {
    float x = xb[idx];
    float xn = fminf(fmaxf(x * inv, -0.99f), 0.99f);
    float u = (xn + 1.f) * 33.f;
    int c0 = (int)floorf(u) - 1;
    float sm[J_N] = {0, 0, 0, 0, 0, 0, 0, 0};
#pragma unroll
    for (int kk = 0; kk < 4; kk++) {
      int c = c0 + kk;
      if (c >= 0 && c < C_N) {
        float bas = bspline(fabsf(u - (float)c));
#pragma unroll
        for (int j = 0; j < J_N; j++) sm[j] += bas * wl[j * C_N + c];
      }
    }
#pragma unroll
    for (int j = 0; j < J_N; j++) {
      float a = sm[j] + aom[j] * x;
      acc[j] += a * a;
    }
  }
  int lane = threadIdx.x & 63, wid = threadIdx.x >> 6;
#pragma unroll
  for (int j = 0; j < J_N; j++) {
    float v = acc[j];
#pragma unroll
    for (int off = 32; off > 0; off >>= 1) v += __shfl_down(v, off, 64);
    if (lane == 0) red[wid * J_N + j] = v;
  }
  __syncthreads();
  if (threadIdx.x < J_N) {
    int j = threadIdx.x;
    float s = red[j] + red[J_N + j] + red[2 * J_N + j] + red[3 * J_N + j];
    float E = s / (float)SF_N;
    float sE = sqrtf(E + 1e-8f);
    float ta = fabsf(tau[i * J_N + j]);
    float tv = fabsf(temp[0]) * SQRT_SF + 1e-4f;
    float mk = 1.f / (1.f + expf(-(sE - ta) / tv));
    maskv[(b * IN_N + i) * J_N + j] = mk;
    g[(b * IN_N + i) * J_N + j] = (sE / (ta + 1e-8f)) * mk;
  }
}

// ---------------- 3. combined[b,j,s,f] ----------------
// grid = (ceil(SF/256), B), 256 threads
__global__ void k_combined(const float* __restrict__ x_in, const float* __restrict__ sw,
                           const float* __restrict__ omiga,
                           const unsigned int* __restrict__ maxbits,
                           const float* __restrict__ maskv, float* __restrict__ comb) {
  int b = blockIdx.y;
  __shared__ float wl[IN_N * J_N * C_N];  // 4288 floats
  __shared__ float aom[IN_N * J_N];
  __shared__ float mk[IN_N * J_N];
  for (int idx = threadIdx.x; idx < IN_N * J_N * C_N; idx += 256) wl[idx] = sw[idx];
  if (threadIdx.x < 64) {
    aom[threadIdx.x] = fabsf(omiga[threadIdx.x]);
    mk[threadIdx.x] = maskv[b * 64 + threadIdx.x];
  }
  __syncthreads();
  int idx = blockIdx.x * 256 + threadIdx.x;
  if (idx >= SF_N) return;
  float maxv = __uint_as_float(*maxbits) + 1e-8f;
  float inv = 0.95f / maxv;
  float cb[J_N] = {0, 0, 0, 0, 0, 0, 0, 0};
  for (int i = 0; i < IN_N; i++) {
    float x = x_in[(b * IN_N + i) * SF_N + idx];
    float xn = fminf(fmaxf(x * inv, -0.99f), 0.99f);
    float u = (xn + 1.f) * 33.f;
    int c0 = (int)floorf(u) - 1;
    float sm[J_N] = {0, 0, 0, 0, 0, 0, 0, 0};
#pragma unroll
    for (int kk = 0; kk < 4; kk++) {
      int c = c0 + kk;
      if (c >= 0 && c < C_N) {
        float bas = bspline(fabsf(u - (float)c));
#pragma unroll
        for (int j = 0; j < J_N; j++) sm[j] += bas * wl[(i * J_N + j) * C_N + c];
      }
    }
#pragma unroll
    for (int j = 0; j < J_N; j++) cb[j] += (sm[j] + aom[i * 8 + j] * x) * mk[i * 8 + j];
  }
#pragma unroll
  for (int j = 0; j < J_N; j++) comb[(b * J_N + j) * SF_N + idx] = cb[j];
}

// ---------------- 4. Kt/Qt build + LN over e=256 ----------------
// one wave per (b,j,s) row; grid = 11968/4 blocks of 256
__global__ void k_ktqt(const float* __restrict__ proj, const float* __restrict__ g,
                       float* __restrict__ ktn, float* __restrict__ qtn) {
  int w = threadIdx.x >> 6, lane = threadIdx.x & 63;
  int gr = blockIdx.x * 4 + w;  // 0..11967
  int bj = gr / S_N, s = gr - bj * S_N;
  int b = bj >> 3, j = bj & 7;
  float kv[4], qv[4];
#pragma unroll
  for (int q = 0; q < 4; q++) {
    kv[q] = proj[((b * 8 + 2 * q) * S_N + s) * 64 + lane] * g[(b * 8 + 2 * q) * 8 + j];
    qv[q] = proj[((b * 8 + 2 * q + 1) * S_N + s) * 64 + lane] * g[(b * 8 + 2 * q + 1) * 8 + j];
  }
  float mkv = wave_sum(kv[0] + kv[1] + kv[2] + kv[3]) * (1.f / 256.f);
  float mqv = wave_sum(qv[0] + qv[1] + qv[2] + qv[3]) * (1.f / 256.f);
  float vk = 0.f, vq = 0.f;
#pragma unroll
  for (int q = 0; q < 4; q++) {
    float dk = kv[q] - mkv; vk += dk * dk;
    float dq = qv[q] - mqv; vq += dq * dq;
  }
  vk = wave_sum(vk) * (1.f / 256.f);
  vq = wave_sum(vq) * (1.f / 256.f);
  float ik = 1.f / sqrtf(vk + 1e-5f);
  float iq = 1.f / sqrtf(vq + 1e-5f);
  float* ko = ktn + gr * E_N;
  float* qo = qtn + gr * E_N;
#pragma unroll
  for (int q = 0; q < 4; q++) {
    ko[q * 64 + lane] = (kv[q] - mkv) * ik;
    qo[q * 64 + lane] = (qv[q] - mqv) * iq;
  }
}

// ---------------- 5. raw = Ktn.Qtn^T (scaled) ----------------
// grid = (3 s-tiles, 3 t-tiles, 64 bj); 256 threads = 16x16, 4x4 acc each
__global__ void k_raw(const float* __restrict__ ktn, const float* __restrict__ qtn,
                      const float* __restrict__ temp, float* __restrict__ w1) {
  int st = blockIdx.x, tt = blockIdx.y, bj = blockIdx.z;
  __shared__ __align__(16) float kt[64 * 68];
  __shared__ __align__(16) float qt[64 * 68];
  int tx = threadIdx.x & 15, ty = threadIdx.x >> 4;
  float acc[4][4] = {};
  for (int ec = 0; ec < 4; ec++) {
    __syncthreads();
    for (int idx = threadIdx.x; idx < 4096; idx += 256) {
      int sl = idx >> 6, el = idx & 63;
      int srow = st * 64 + sl;
      kt[el * 68 + sl] = (srow < S_N) ? ktn[(bj * S_N + srow) * E_N + ec * 64 + el] : 0.f;
      int trow = tt * 64 + sl;
      qt[el * 68 + sl] = (trow < S_N) ? qtn[(bj * S_N + trow) * E_N + ec * 64 + el] : 0.f;
    }
    __syncthreads();
#pragma unroll 8
    for (int e = 0; e < 64; e++) {
      float4 kf = *(const float4*)(kt + e * 68 + tx * 4);
      float4 qf = *(const float4*)(qt + e * 68 + ty * 4);
      acc[0][0] += kf.x * qf.x; acc[0][1] += kf.x * qf.y; acc[0][2] += kf.x * qf.z; acc[0][3] += kf.x * qf.w;
      acc[1][0] += kf.y * qf.x; acc[1][1] += kf.y * qf.y; acc[1][2] += kf.y * qf.z; acc[1][3] += kf.y * qf.w;
      acc[2][0] += kf.z * qf.x; acc[2][1] += kf.z * qf.y; acc[2][2] += kf.z * qf.z; acc[2][3] += kf.z * qf.w;
      acc[3][0] += kf.w * qf.x; acc[3][1] += kf.w * qf.y; acc[3][2] += kf.w * qf.z; acc[3][3] += kf.w * qf.w;
    }
  }
  float tv = fabsf(temp[0]) * SQRT_SF + 1e-4f;
  float scale = 1.f / (16.f * tv);
#pragma unroll
  for (int m = 0; m < 4; m++) {
    int s = st * 64 + tx * 4 + m;
    if (s >= S_N) continue;
#pragma unroll
    for (int n = 0; n < 4; n++) {
      int t = tt * 64 + ty * 4 + n;
      if (t < S_N) w1[(bj * S_N + s) * S_N + t] = acc[m][n] * scale;
    }
  }
}

// ---------------- 6. row softmax, in place ----------------
// one wave per row; grid = 11968/4
__global__ void k_softmax(float* __restrict__ w1) {
  int w = threadIdx.x >> 6, lane = threadIdx.x & 63;
  int row = blockIdx.x * 4 + w;
  float* p = w1 + (long)row * S_N;
  float v[3];
  float m = -1e30f;
#pragma unroll
  for (int q = 0; q < 3; q++) {
    int t = lane + q * 64;
    v[q] = (t < S_N) ? p[t] : -1e30f;
    m = fmaxf(m, v[q]);
  }
  m = wave_max(m);
  float ssum = 0.f;
#pragma unroll
  for (int q = 0; q < 3; q++) {
    int t = lane + q * 64;
    float e = (t < S_N) ? expf(v[q] - m) : 0.f;
    v[q] = e;
    ssum += e;
  }
  ssum = wave_sum(ssum);
  float invs = 1.f / ssum;
#pragma unroll
  for (int q = 0; q < 3; q++) {
    int t = lane + q * 64;
    if (t < S_N) p[t] = v[q] * invs;
  }
}

// ---------------- 7. LN(combined)*W2 + b -> x_prime ----------------
// one wave per (b,j,s) row
__global__ void k_xprime(const float* __restrict__ comb, const float* __restrict__ W2,
                         const float* __restrict__ bparam, const float* __restrict__ lns,
                         const float* __restrict__ lnb, float* __restrict__ xprime) {
  int w = threadIdx.x >> 6, lane = threadIdx.x & 63;
  int gr = blockIdx.x * 4 + w;
  int bj = gr / S_N, s = gr - bj * S_N;
  int j = bj & 7;
  float x = comb[(long)gr * 64 + lane];
  float m = wave_sum(x) * (1.f / 64.f);
  float d = x - m;
  float var = wave_sum(d * d) * (1.f / 64.f);
  float xln = d / sqrtf(var + 1e-5f) * lns[j * 64 + lane] + lnb[j * 64 + lane];
  float acc = bparam[(j * S_N + s) * 64 + lane];
  const float* w2j = W2 + j * 64 * 64;
#pragma unroll 8
  for (int h = 0; h < 64; h++) acc += __shfl(xln, h, 64) * w2j[h * 64 + lane];
  xprime[(long)gr * 64 + lane] = acc;
}

// ---------------- 8. final: attn apply + conv + residuals ----------------
// grid = (24 s-tiles of 8, 64 bj); 256 threads
__global__ void k_final(const float* __restrict__ xprime, const float* __restrict__ w1,
                        const float* __restrict__ comb, const float* __restrict__ w3,
                        const float* __restrict__ alpha, const float* __restrict__ beta,
                        const float* __restrict__ theta, const float* __restrict__ gamma,
                        float* __restrict__ out) {
  int tile = blockIdx.x, bj = blockIdx.y;
  int j = bj & 7;
  __shared__ float xp[S_N * 64];    // 47872 B
  __shared__ float w1t[8 * S_N];    // 5984 B
  __shared__ float w3l[64 * KS_N];  // 3840 B
  const float* xpg = xprime + (long)bj * (S_N * 64);
  for (int idx = threadIdx.x; idx < S_N * 64; idx += 256) xp[idx] = xpg[idx];
  int s0 = tile * 8;
  for (int idx = threadIdx.x; idx < 8 * S_N; idx += 256) {
    int r = idx / S_N, t = idx - r * S_N;
    int srow = s0 + r;
    w1t[idx] = (srow < S_N) ? w1[((long)bj * S_N + srow) * S_N + t] : 0.f;
  }
  for (int idx = threadIdx.x; idx < 64 * KS_N; idx += 256) w3l[idx] = w3[j * 64 * KS_N + idx];
  __syncthreads();
  int w = threadIdx.x >> 6, o = threadIdx.x & 63;
  float aa = fabsf(alpha[j]), ba = fabsf(beta[j]), ta = fabsf(theta[j]), gv = gamma[j];
  int r0 = w * 2;
  float acc0 = 0.f, acc1 = 0.f;
  for (int t = 0; t < S_N; t++) {
    float xv = xp[t * 64 + o];
    acc0 += w1t[r0 * S_N + t] * xv;
    acc1 += w1t[(r0 + 1) * S_N + t] * xv;
  }
#pragma unroll
  for (int rr = 0; rr < 2; rr++) {
    int s = s0 + r0 + rr;
    if (s >= S_N) continue;
    float acc = rr ? acc1 : acc0;
    float conv = 0.f;
#pragma unroll
    for (int k = 0; k < KS_N; k++) {
      int si = s + k - 7;
      if (si >= 0 && si < S_N) conv += xp[si * 64 + o] * w3l[o * KS_N + k];
    }
    float res = ba * acc + aa * xp[s * 64 + o] + ta * conv +
                gv * comb[((long)bj * S_N + s) * 64 + o];
    out[((long)bj * S_N + s) * 64 + o] = res;
  }
}

extern "C" void kernel_launch(void* const* d_in, const int* in_sizes, int n_in,
                              void* d_out, int out_size, void* d_ws, size_t ws_size,
                              hipStream_t stream) {
  const float* x_in   = (const float*)d_in[0];
  const float* proj   = (const float*)d_in[1];
  const float* sw     = (const float*)d_in[2];
  const float* tau    = (const float*)d_in[3];
  const float* temp   = (const float*)d_in[4];
  const float* omiga  = (const float*)d_in[5];
  const float* W2     = (const float*)d_in[6];
  const float* bparam = (const float*)d_in[7];
  const float* lns    = (const float*)d_in[8];
  const float* lnb    = (const float*)d_in[9];
  const float* alpha  = (const float*)d_in[10];
  const float* beta   = (const float*)d_in[11];
  const float* theta  = (const float*)d_in[12];
  const float* gamma  = (const float*)d_in[13];
  const float* w3     = (const float*)d_in[14];

  float* out = (float*)d_out;
  float* xprime = out + B_N * J_N * S_N * O_N;  // second output, written directly

  float* wsf = (float*)d_ws;
  unsigned int* maxb = (unsigned int*)d_ws;   // [0]
  float* maskv = wsf + 256;                   // 512
  float* g     = wsf + 768;                   // 512
  float* ktn   = wsf + 2048;                  // B*J*S*256 = 3,063,808
  float* qtn   = ktn + B_N * J_N * S_N * E_N;
  float* w1    = qtn + B_N * J_N * S_N * E_N; // B*J*S*S = 2,238,016
  float* comb  = w1 + B_N * J_N * S_N * S_N;  // B*J*S*F = 765,952

  hipMemsetAsync(d_ws, 0, 1024, stream);
  k_maxabs<<<1024, 256, 0, stream>>>(x_in, maxb, B_N * IN_N * S_N * F_N);
  k_energy<<<B_N * IN_N, 256, 0, stream>>>(x_in, sw, tau, temp, omiga, maxb, maskv, g);
  k_combined<<<dim3((SF_N + 255) / 256, B_N), 256, 0, stream>>>(x_in, sw, omiga, maxb, maskv, comb);
  k_ktqt<<<(B_N * J_N * S_N) / 4, 256, 0, stream>>>(proj, g, ktn, qtn);
  k_raw<<<dim3(3, 3, 64), 256, 0, stream>>>(ktn, qtn, temp, w1);
  k_softmax<<<(B_N * J_N * S_N) / 4, 256, 0, stream>>>(w1);
  k_xprime<<<(B_N * J_N * S_N) / 4, 256, 0, stream>>>(comb, W2, bparam, lns, lnb, xprime);
  k_final<<<dim3(24, 64), 256, 0, stream>>>(xprime, w1, comb, w3, alpha, beta, theta, gamma, out);
}

// Round 2
// 268.639 us; speedup vs baseline: 1.1703x; 1.1703x over previous
//
#include <hip/hip_runtime.h>
#include <math.h>

#define B_N 8
#define IN_N 8
#define J_N 8
#define S_N 187
#define F_N 64
#define O_N 64
#define C_N 67
#define KS_N 15
#define SF_N (S_N * F_N)   // 11968
#define E_N 256
#define ROWS_N (B_N * J_N * S_N)  // 11968
#define SQRT_SF 0.85467470f  // sqrt(187/256)

typedef __attribute__((ext_vector_type(8))) _Float16 half8;
typedef __attribute__((ext_vector_type(4))) float floatx4;

// ---------------- wave helpers (wave = 64) ----------------
__device__ __forceinline__ float wave_sum(float v) {
#pragma unroll
  for (int off = 32; off > 0; off >>= 1) v += __shfl_down(v, off, 64);
  return __shfl(v, 0, 64);
}
__device__ __forceinline__ float wave_max(float v) {
#pragma unroll
  for (int off = 32; off > 0; off >>= 1) v = fmaxf(v, __shfl_down(v, off, 64));
  return __shfl(v, 0, 64);
}

__device__ __forceinline__ float bspline(float d) {
  float t2 = fmaxf(2.f - d, 0.f);
  float t1 = fmaxf(1.f - d, 0.f);
  return t2 * t2 * t2 * (1.f / 6.f) - t1 * t1 * t1 * (4.f / 6.f);
}

// ---------------- 1. global max |x| ----------------
__global__ void k_maxabs(const float* __restrict__ x, unsigned int* __restrict__ out, int n) {
  int tid = blockIdx.x * blockDim.x + threadIdx.x;
  float m = 0.f;
  for (int i = tid; i < n; i += gridDim.x * blockDim.x) m = fmaxf(m, fabsf(x[i]));
  m = wave_max(m);
  if ((threadIdx.x & 63) == 0) atomicMax(out, __float_as_uint(m));
}

// ---------------- 2a. energy partial sums ----------------
// grid = B*IN*4 blocks, 256 threads; chunk = SF/4 = 2992
__global__ void k_energy_part(const float* __restrict__ x_in, const float* __restrict__ sw,
                              const float* __restrict__ omiga,
                              const unsigned int* __restrict__ maxbits,
                              float* __restrict__ esum) {
  int bi = blockIdx.x >> 2, chunk = blockIdx.x & 3;
  int i = bi & 7;
  __shared__ float wl[J_N * C_N];
  __shared__ float aom[J_N];
  for (int idx = threadIdx.x; idx < J_N * C_N; idx += 256) wl[idx] = sw[i * J_N * C_N + idx];
  if (threadIdx.x < J_N) aom[threadIdx.x] = fabsf(omiga[i * J_N + threadIdx.x]);
  __syncthreads();
  float maxv = __uint_as_float(*maxbits) + 1e-8f;
  float inv = 0.95f / maxv;
  float acc[J_N] = {0, 0, 0, 0, 0, 0, 0, 0};
  const float* xb = x_in + (long)bi * SF_N;
  int lo = chunk * 2992, hi = lo + 2992;
  for (int idx = lo + threadIdx.x; idx < hi; idx += 256) {
    float x = xb[idx];
    float xn = fminf(fmaxf(x * inv, -0.99f), 0.99f);
    float u = (xn + 1.f) * 33.f;
    int c0 = (int)floorf(u) - 1;
    float sm[J_N] = {0, 0, 0, 0, 0, 0, 0, 0};
#pragma unroll
    for (int kk = 0; kk < 4; kk++) {
      int c = c0 + kk;
      if (c >= 0 && c < C_N) {
        float bas = bspline(fabsf(u - (float)c));
#pragma unroll
        for (int j = 0; j < J_N; j++) sm[j] += bas * wl[j * C_N + c];
      }
    }
#pragma unroll
    for (int j = 0; j < J_N; j++) {
      float a = sm[j] + aom[j] * x;
      acc[j] += a * a;
    }
  }
  int lane = threadIdx.x & 63;
#pragma unroll
  for (int j = 0; j < J_N; j++) {
    float v = acc[j];
#pragma unroll
    for (int off = 32; off > 0; off >>= 1) v += __shfl_down(v, off, 64);
    if (lane == 0) atomicAdd(&esum[bi * J_N + j], v);
  }
}

// ---------------- 2b. finalize mask/g ----------------
// 1 block, 512 threads
__global__ void k_energy_fin(const float* __restrict__ esum, const float* __restrict__ tau,
                             const float* __restrict__ temp,
                             float* __restrict__ maskv, float* __restrict__ g) {
  int bij = threadIdx.x;  // (b*8+i)*8+j
  int ij = bij & 63;
  float E = esum[bij] / (float)SF_N;
  float sE = sqrtf(E + 1e-8f);
  float ta = fabsf(tau[ij]);
  float tv = fabsf(temp[0]) * SQRT_SF + 1e-4f;
  float mk = 1.f / (1.f + expf(-(sE - ta) / tv));
  maskv[bij] = mk;
  g[bij] = (sE / (ta + 1e-8f)) * mk;
}

// ---------------- 3. combined[b,j,s,f] ----------------
__global__ void k_combined(const float* __restrict__ x_in, const float* __restrict__ sw,
                           const float* __restrict__ omiga,
                           const unsigned int* __restrict__ maxbits,
                           const float* __restrict__ maskv, float* __restrict__ comb) {
  int b = blockIdx.y;
  __shared__ float wl[IN_N * J_N * C_N];
  __shared__ float aom[IN_N * J_N];
  __shared__ float mk[IN_N * J_N];
  for (int idx = threadIdx.x; idx < IN_N * J_N * C_N; idx += 256) wl[idx] = sw[idx];
  if (threadIdx.x < 64) {
    aom[threadIdx.x] = fabsf(omiga[threadIdx.x]);
    mk[threadIdx.x] = maskv[b * 64 + threadIdx.x];
  }
  __syncthreads();
  int idx = blockIdx.x * 256 + threadIdx.x;
  if (idx >= SF_N) return;
  float maxv = __uint_as_float(*maxbits) + 1e-8f;
  float inv = 0.95f / maxv;
  float cb[J_N] = {0, 0, 0, 0, 0, 0, 0, 0};
  for (int i = 0; i < IN_N; i++) {
    float x = x_in[(b * IN_N + i) * SF_N + idx];
    float xn = fminf(fmaxf(x * inv, -0.99f), 0.99f);
    float u = (xn + 1.f) * 33.f;
    int c0 = (int)floorf(u) - 1;
    float sm[J_N] = {0, 0, 0, 0, 0, 0, 0, 0};
#pragma unroll
    for (int kk = 0; kk < 4; kk++) {
      int c = c0 + kk;
      if (c >= 0 && c < C_N) {
        float bas = bspline(fabsf(u - (float)c));
#pragma unroll
        for (int j = 0; j < J_N; j++) sm[j] += bas * wl[(i * J_N + j) * C_N + c];
      }
    }
#pragma unroll
    for (int j = 0; j < J_N; j++) cb[j] += (sm[j] + aom[i * 8 + j] * x) * mk[i * 8 + j];
  }
#pragma unroll
  for (int j = 0; j < J_N; j++) comb[(b * J_N + j) * SF_N + idx] = cb[j];
}

// ---------------- 4. Kt/Qt build + LN, output split f16 hi/lo ----------------
// one wave per (b,j,s) row; grid = 11968/4 blocks of 256
__global__ void k_ktqt(const float* __restrict__ proj, const float* __restrict__ g,
                       _Float16* __restrict__ khi, _Float16* __restrict__ klo,
                       _Float16* __restrict__ qhi, _Float16* __restrict__ qlo) {
  int w = threadIdx.x >> 6, lane = threadIdx.x & 63;
  int gr = blockIdx.x * 4 + w;  // 0..11967
  int bj = gr / S_N, s = gr - bj * S_N;
  int b = bj >> 3, j = bj & 7;
  float kv[4], qv[4];
#pragma unroll
  for (int q = 0; q < 4; q++) {
    kv[q] = proj[((b * 8 + 2 * q) * S_N + s) * 64 + lane] * g[(b * 8 + 2 * q) * 8 + j];
    qv[q] = proj[((b * 8 + 2 * q + 1) * S_N + s) * 64 + lane] * g[(b * 8 + 2 * q + 1) * 8 + j];
  }
  float mkv = wave_sum(kv[0] + kv[1] + kv[2] + kv[3]) * (1.f / 256.f);
  float mqv = wave_sum(qv[0] + qv[1] + qv[2] + qv[3]) * (1.f / 256.f);
  float vk = 0.f, vq = 0.f;
#pragma unroll
  for (int q = 0; q < 4; q++) {
    float dk = kv[q] - mkv; vk += dk * dk;
    float dq = qv[q] - mqv; vq += dq * dq;
  }
  vk = wave_sum(vk) * (1.f / 256.f);
  vq = wave_sum(vq) * (1.f / 256.f);
  float ik = 1.f / sqrtf(vk + 1e-5f);
  float iq = 1.f / sqrtf(vq + 1e-5f);
  long base = (long)gr * E_N;
#pragma unroll
  for (int q = 0; q < 4; q++) {
    float fk = (kv[q] - mkv) * ik;
    float fq = (qv[q] - mqv) * iq;
    _Float16 hk = (_Float16)fk;
    _Float16 hq = (_Float16)fq;
    khi[base + q * 64 + lane] = hk;
    klo[base + q * 64 + lane] = (_Float16)(fk - (float)hk);
    qhi[base + q * 64 + lane] = hq;
    qlo[base + q * 64 + lane] = (_Float16)(fq - (float)hq);
  }
}

// ---------------- 5. raw = Ktn.Qtn^T via split-f16 MFMA ----------------
// grid = (3 s-tiles, 3 t-tiles, 64 bj); 256 threads = 4 waves
// wave w computes s-rows [st*64+w*16, +16) x t-cols [tt*64, +64) with
// 16x16x32 f16 MFMA; fp32-accurate via hi/lo split (3 MFMAs per tile-step).
__global__ void k_raw(const _Float16* __restrict__ khi, const _Float16* __restrict__ klo,
                      const _Float16* __restrict__ qhi, const _Float16* __restrict__ qlo,
                      const float* __restrict__ temp, float* __restrict__ w1) {
  int st = blockIdx.x, tt = blockIdx.y, bj = blockIdx.z;
  int wave = threadIdx.x >> 6, lane = threadIdx.x & 63;
  int quad = lane >> 4, m16 = lane & 15;
  int ebase = quad * 8;
  // A fragment row (clamped; out-of-range rows computed but not stored)
  int mrow = st * 64 + wave * 16 + m16;
  if (mrow > S_N - 1) mrow = S_N - 1;
  long aoff = ((long)bj * S_N + mrow) * E_N + ebase;
  const _Float16* ah_p = khi + aoff;
  const _Float16* al_p = klo + aoff;
  // B fragment rows, 4 t-tiles of 16
  const _Float16* bh_p[4];
  const _Float16* bl_p[4];
#pragma unroll
  for (int n = 0; n < 4; n++) {
    int t = tt * 64 + n * 16 + m16;
    if (t > S_N - 1) t = S_N - 1;
    long boff = ((long)bj * S_N + t) * E_N + ebase;
    bh_p[n] = qhi + boff;
    bl_p[n] = qlo + boff;
  }
  floatx4 acc[4] = {};
  for (int ec = 0; ec < 8; ec++) {
    half8 ah = *(const half8*)(ah_p + ec * 32);
    half8 al = *(const half8*)(al_p + ec * 32);
#pragma unroll
    for (int n = 0; n < 4; n++) {
      half8 bh = *(const half8*)(bh_p[n] + ec * 32);
      half8 bl = *(const half8*)(bl_p[n] + ec * 32);
      acc[n] = __builtin_amdgcn_mfma_f32_16x16x32_f16(ah, bh, acc[n], 0, 0, 0);
      acc[n] = __builtin_amdgcn_mfma_f32_16x16x32_f16(al, bh, acc[n], 0, 0, 0);
      acc[n] = __builtin_amdgcn_mfma_f32_16x16x32_f16(ah, bl, acc[n], 0, 0, 0);
    }
  }
  float tv = fabsf(temp[0]) * SQRT_SF + 1e-4f;
  float scale = 1.f / (16.f * tv);
#pragma unroll
  for (int n = 0; n < 4; n++) {
    int t = tt * 64 + n * 16 + m16;  // D col = lane&15
    if (t >= S_N) continue;
#pragma unroll
    for (int r = 0; r < 4; r++) {
      int s = st * 64 + wave * 16 + quad * 4 + r;  // D row = quad*4+reg
      if (s < S_N) w1[((long)bj * S_N + s) * S_N + t] = acc[n][r] * scale;
    }
  }
}

// ---------------- 6. row softmax, in place ----------------
__global__ void k_softmax(float* __restrict__ w1) {
  int w = threadIdx.x >> 6, lane = threadIdx.x & 63;
  int row = blockIdx.x * 4 + w;
  float* p = w1 + (long)row * S_N;
  float v[3];
  float m = -1e30f;
#pragma unroll
  for (int q = 0; q < 3; q++) {
    int t = lane + q * 64;
    v[q] = (t < S_N) ? p[t] : -1e30f;
    m = fmaxf(m, v[q]);
  }
  m = wave_max(m);
  float ssum = 0.f;
#pragma unroll
  for (int q = 0; q < 3; q++) {
    int t = lane + q * 64;
    float e = (t < S_N) ? expf(v[q] - m) : 0.f;
    v[q] = e;
    ssum += e;
  }
  ssum = wave_sum(ssum);
  float invs = 1.f / ssum;
#pragma unroll
  for (int q = 0; q < 3; q++) {
    int t = lane + q * 64;
    if (t < S_N) p[t] = v[q] * invs;
  }
}

// ---------------- 7. LN(combined)*W2 + b -> x_prime ----------------
__global__ void k_xprime(const float* __restrict__ comb, const float* __restrict__ W2,
                         const float* __restrict__ bparam, const float* __restrict__ lns,
                         const float* __restrict__ lnb, float* __restrict__ xprime) {
  int w = threadIdx.x >> 6, lane = threadIdx.x & 63;
  int gr = blockIdx.x * 4 + w;
  int bj = gr / S_N, s = gr - bj * S_N;
  int j = bj & 7;
  float x = comb[(long)gr * 64 + lane];
  float m = wave_sum(x) * (1.f / 64.f);
  float d = x - m;
  float var = wave_sum(d * d) * (1.f / 64.f);
  float xln = d / sqrtf(var + 1e-5f) * lns[j * 64 + lane] + lnb[j * 64 + lane];
  float acc = bparam[(j * S_N + s) * 64 + lane];
  const float* w2j = W2 + j * 64 * 64;
#pragma unroll 8
  for (int h = 0; h < 64; h++) acc += __shfl(xln, h, 64) * w2j[h * 64 + lane];
  xprime[(long)gr * 64 + lane] = acc;
}

// ---------------- 8. final: attn apply + conv + residuals ----------------
// grid = (12 s-tiles of 16, 64 bj); 256 threads; wave w -> rows w*4..w*4+3
__global__ void k_final(const float* __restrict__ xprime, const float* __restrict__ w1,
                        const float* __restrict__ comb, const float* __restrict__ w3,
                        const float* __restrict__ alpha, const float* __restrict__ beta,
                        const float* __restrict__ theta, const float* __restrict__ gamma,
                        float* __restrict__ out) {
  int tile = blockIdx.x, bj = blockIdx.y;
  int j = bj & 7;
  __shared__ float xp[S_N * 64];     // 47872 B
  __shared__ float w1t[16 * 188];    // 12032 B (pad to 188, float4-aligned rows)
  __shared__ float w3l[64 * KS_N];   // 3840 B
  const float4* xpg4 = (const float4*)(xprime + (long)bj * (S_N * 64));
  float4* xp4 = (float4*)xp;
  for (int idx = threadIdx.x; idx < S_N * 16; idx += 256) xp4[idx] = xpg4[idx];
  int s0 = tile * 16;
  for (int idx = threadIdx.x; idx < 16 * S_N; idx += 256) {
    int r = idx / S_N, t = idx - r * S_N;
    int srow = s0 + r;
    w1t[r * 188 + t] = (srow < S_N) ? w1[((long)bj * S_N + srow) * S_N + t] : 0.f;
  }
  for (int idx = threadIdx.x; idx < 64 * KS_N; idx += 256) w3l[idx] = w3[j * 64 * KS_N + idx];
  __syncthreads();
  int w = threadIdx.x >> 6, o = threadIdx.x & 63;
  float aa = fabsf(alpha[j]), ba = fabsf(beta[j]), ta = fabsf(theta[j]), gv = gamma[j];
  float acc[4] = {0.f, 0.f, 0.f, 0.f};
  for (int t = 0; t < 184; t += 4) {
    float x0 = xp[t * 64 + o];
    float x1 = xp[(t + 1) * 64 + o];
    float x2 = xp[(t + 2) * 64 + o];
    float x3 = xp[(t + 3) * 64 + o];
#pragma unroll
    for (int rr = 0; rr < 4; rr++) {
      float4 wv = *(const float4*)&w1t[(w * 4 + rr) * 188 + t];
      acc[rr] += wv.x * x0 + wv.y * x1 + wv.z * x2 + wv.w * x3;
    }
  }
#pragma unroll
  for (int t = 184; t < S_N; t++) {
    float xv = xp[t * 64 + o];
#pragma unroll
    for (int rr = 0; rr < 4; rr++) acc[rr] += w1t[(w * 4 + rr) * 188 + t] * xv;
  }
#pragma unroll
  for (int rr = 0; rr < 4; rr++) {
    int s = s0 + w * 4 + rr;
    if (s >= S_N) continue;
    float conv = 0.f;
#pragma unroll
    for (int k = 0; k < KS_N; k++) {
      int si = s + k - 7;
      if (si >= 0 && si < S_N) conv += xp[si * 64 + o] * w3l[o * KS_N + k];
    }
    float res = ba * acc[rr] + aa * xp[s * 64 + o] + ta * conv +
                gv * comb[((long)bj * S_N + s) * 64 + o];
    out[((long)bj * S_N + s) * 64 + o] = res;
  }
}

extern "C" void kernel_launch(void* const* d_in, const int* in_sizes, int n_in,
                              void* d_out, int out_size, void* d_ws, size_t ws_size,
                              hipStream_t stream) {
  const float* x_in   = (const float*)d_in[0];
  const float* proj   = (const float*)d_in[1];
  const float* sw     = (const float*)d_in[2];
  const float* tau    = (const float*)d_in[3];
  const float* temp   = (const float*)d_in[4];
  const float* omiga  = (const float*)d_in[5];
  const float* W2     = (const float*)d_in[6];
  const float* bparam = (const float*)d_in[7];
  const float* lns    = (const float*)d_in[8];
  const float* lnb    = (const float*)d_in[9];
  const float* alpha  = (const float*)d_in[10];
  const float* beta   = (const float*)d_in[11];
  const float* theta  = (const float*)d_in[12];
  const float* gamma  = (const float*)d_in[13];
  const float* w3     = (const float*)d_in[14];

  float* out = (float*)d_out;
  float* xprime = out + B_N * J_N * S_N * O_N;  // second output, written directly

  float* wsf = (float*)d_ws;
  unsigned int* maxb = (unsigned int*)d_ws;       // wsf[0]
  float* esum  = wsf + 64;                        // 512 floats (within memset range? 64..575)
  float* maskv = wsf + 640;                       // 512 floats
  float* g     = wsf + 1152;                      // 512 floats
  const long RE = (long)ROWS_N * E_N;             // 3,063,808 halves per array
  _Float16* khi = (_Float16*)(wsf + 2048);
  _Float16* klo = khi + RE;
  _Float16* qhi = klo + RE;
  _Float16* qlo = qhi + RE;
  float* w1   = wsf + 2048 + 2 * RE;              // RE halves = RE/2 floats; 4 arrays = 2*RE floats
  float* comb = w1 + (long)B_N * J_N * S_N * S_N; // 2,238,016 floats

  // zero maxb + esum (wsf[0..575] = 2304 bytes)
  hipMemsetAsync(d_ws, 0, 2304, stream);
  k_maxabs<<<1024, 256, 0, stream>>>(x_in, maxb, B_N * IN_N * S_N * F_N);
  k_energy_part<<<B_N * IN_N * 4, 256, 0, stream>>>(x_in, sw, omiga, maxb, esum);
  k_energy_fin<<<1, 512, 0, stream>>>(esum, tau, temp, maskv, g);
  k_combined<<<dim3((SF_N + 255) / 256, B_N), 256, 0, stream>>>(x_in, sw, omiga, maxb, maskv, comb);
  k_ktqt<<<ROWS_N / 4, 256, 0, stream>>>(proj, g, khi, klo, qhi, qlo);
  k_raw<<<dim3(3, 3, 64), 256, 0, stream>>>(khi, klo, qhi, qlo, temp, w1);
  k_softmax<<<ROWS_N / 4, 256, 0, stream>>>(w1);
  k_xprime<<<ROWS_N / 4, 256, 0, stream>>>(comb, W2, bparam, lns, lnb, xprime);
  k_final<<<dim3(12, 64), 256, 0, stream>>>(xprime, w1, comb, w3, alpha, beta, theta, gamma, out);
}

// Round 3
// 222.215 us; speedup vs baseline: 1.4148x; 1.2089x over previous
//
#include <hip/hip_runtime.h>
#include <math.h>

#define B_N 8
#define IN_N 8
#define J_N 8
#define S_N 187
#define F_N 64
#define O_N 64
#define C_N 67
#define KS_N 15
#define SF_N (S_N * F_N)   // 11968
#define E_N 256
#define ROWS_N (B_N * J_N * S_N)  // 11968
#define SQRT_SF 0.85467470f  // sqrt(187/256)

typedef __attribute__((ext_vector_type(8))) _Float16 half8;
typedef __attribute__((ext_vector_type(4))) float floatx4;

// ---------------- wave helpers (wave = 64) ----------------
__device__ __forceinline__ float wave_sum(float v) {
#pragma unroll
  for (int off = 32; off > 0; off >>= 1) v += __shfl_down(v, off, 64);
  return __shfl(v, 0, 64);
}
__device__ __forceinline__ float wave_max(float v) {
#pragma unroll
  for (int off = 32; off > 0; off >>= 1) v = fmaxf(v, __shfl_down(v, off, 64));
  return __shfl(v, 0, 64);
}

__device__ __forceinline__ float bspline(float d) {
  float t2 = fmaxf(2.f - d, 0.f);
  float t1 = fmaxf(1.f - d, 0.f);
  return t2 * t2 * t2 * (1.f / 6.f) - t1 * t1 * t1 * (4.f / 6.f);
}

// ---------------- 1. global max |x| ----------------
// 64 blocks x 256 thr, float4 loads, one atomic per block (was 4096 same-addr
// atomics = 49.7 us of pure serialization)
__global__ void k_maxabs(const float4* __restrict__ x, unsigned int* __restrict__ out, int n4) {
  __shared__ float red[4];
  int tid = blockIdx.x * 256 + threadIdx.x;
  float m = 0.f;
  for (int i = tid; i < n4; i += gridDim.x * 256) {
    float4 v = x[i];
    m = fmaxf(m, fmaxf(fmaxf(fabsf(v.x), fabsf(v.y)), fmaxf(fabsf(v.z), fabsf(v.w))));
  }
  m = wave_max(m);
  if ((threadIdx.x & 63) == 0) red[threadIdx.x >> 6] = m;
  __syncthreads();
  if (threadIdx.x == 0) {
    float bm = fmaxf(fmaxf(red[0], red[1]), fmaxf(red[2], red[3]));
    atomicMax(out, __float_as_uint(bm));
  }
}

// ---------------- 2a. energy partial sums ----------------
// grid = B*IN*4 blocks, 256 threads; chunk = SF/4 = 2992
__global__ void k_energy_part(const float* __restrict__ x_in, const float* __restrict__ sw,
                              const float* __restrict__ omiga,
                              const unsigned int* __restrict__ maxbits,
                              float* __restrict__ esum) {
  int bi = blockIdx.x >> 2, chunk = blockIdx.x & 3;
  int i = bi & 7;
  __shared__ float wl[J_N * C_N];
  __shared__ float aom[J_N];
  for (int idx = threadIdx.x; idx < J_N * C_N; idx += 256) wl[idx] = sw[i * J_N * C_N + idx];
  if (threadIdx.x < J_N) aom[threadIdx.x] = fabsf(omiga[i * J_N + threadIdx.x]);
  __syncthreads();
  float maxv = __uint_as_float(*maxbits) + 1e-8f;
  float inv = 0.95f / maxv;
  float acc[J_N] = {0, 0, 0, 0, 0, 0, 0, 0};
  const float* xb = x_in + (long)bi * SF_N;
  int lo = chunk * 2992, hi = lo + 2992;
  for (int idx = lo + threadIdx.x; idx < hi; idx += 256) {
    float x = xb[idx];
    float xn = fminf(fmaxf(x * inv, -0.99f), 0.99f);
    float u = (xn + 1.f) * 33.f;
    int c0 = (int)floorf(u) - 1;
    float sm[J_N] = {0, 0, 0, 0, 0, 0, 0, 0};
#pragma unroll
    for (int kk = 0; kk < 4; kk++) {
      int c = c0 + kk;
      if (c >= 0 && c < C_N) {
        float bas = bspline(fabsf(u - (float)c));
#pragma unroll
        for (int j = 0; j < J_N; j++) sm[j] += bas * wl[j * C_N + c];
      }
    }
#pragma unroll
    for (int j = 0; j < J_N; j++) {
      float a = sm[j] + aom[j] * x;
      acc[j] += a * a;
    }
  }
  int lane = threadIdx.x & 63;
#pragma unroll
  for (int j = 0; j < J_N; j++) {
    float v = acc[j];
#pragma unroll
    for (int off = 32; off > 0; off >>= 1) v += __shfl_down(v, off, 64);
    if (lane == 0) atomicAdd(&esum[bi * J_N + j], v);
  }
}

// ---------------- 2b. finalize mask/g ----------------
__global__ void k_energy_fin(const float* __restrict__ esum, const float* __restrict__ tau,
                             const float* __restrict__ temp,
                             float* __restrict__ maskv, float* __restrict__ g) {
  int bij = threadIdx.x;  // (b*8+i)*8+j
  int ij = bij & 63;
  float E = esum[bij] / (float)SF_N;
  float sE = sqrtf(E + 1e-8f);
  float ta = fabsf(tau[ij]);
  float tv = fabsf(temp[0]) * SQRT_SF + 1e-4f;
  float mk = 1.f / (1.f + expf(-(sE - ta) / tv));
  maskv[bij] = mk;
  g[bij] = (sE / (ta + 1e-8f)) * mk;
}

// ---------------- 3. combined[b,j,s,f] ----------------
__global__ void k_combined(const float* __restrict__ x_in, const float* __restrict__ sw,
                           const float* __restrict__ omiga,
                           const unsigned int* __restrict__ maxbits,
                           const float* __restrict__ maskv, float* __restrict__ comb) {
  int b = blockIdx.y;
  __shared__ float wl[IN_N * J_N * C_N];
  __shared__ float aom[IN_N * J_N];
  __shared__ float mk[IN_N * J_N];
  for (int idx = threadIdx.x; idx < IN_N * J_N * C_N; idx += 256) wl[idx] = sw[idx];
  if (threadIdx.x < 64) {
    aom[threadIdx.x] = fabsf(omiga[threadIdx.x]);
    mk[threadIdx.x] = maskv[b * 64 + threadIdx.x];
  }
  __syncthreads();
  int idx = blockIdx.x * 256 + threadIdx.x;
  if (idx >= SF_N) return;
  float maxv = __uint_as_float(*maxbits) + 1e-8f;
  float inv = 0.95f / maxv;
  float cb[J_N] = {0, 0, 0, 0, 0, 0, 0, 0};
  for (int i = 0; i < IN_N; i++) {
    float x = x_in[(b * IN_N + i) * SF_N + idx];
    float xn = fminf(fmaxf(x * inv, -0.99f), 0.99f);
    float u = (xn + 1.f) * 33.f;
    int c0 = (int)floorf(u) - 1;
    float sm[J_N] = {0, 0, 0, 0, 0, 0, 0, 0};
#pragma unroll
    for (int kk = 0; kk < 4; kk++) {
      int c = c0 + kk;
      if (c >= 0 && c < C_N) {
        float bas = bspline(fabsf(u - (float)c));
#pragma unroll
        for (int j = 0; j < J_N; j++) sm[j] += bas * wl[(i * J_N + j) * C_N + c];
      }
    }
#pragma unroll
    for (int j = 0; j < J_N; j++) cb[j] += (sm[j] + aom[i * 8 + j] * x) * mk[i * 8 + j];
  }
#pragma unroll
  for (int j = 0; j < J_N; j++) comb[(b * J_N + j) * SF_N + idx] = cb[j];
}

// ---------------- 4. Kt/Qt build + LN, output split f16 hi/lo ----------------
__global__ void k_ktqt(const float* __restrict__ proj, const float* __restrict__ g,
                       _Float16* __restrict__ khi, _Float16* __restrict__ klo,
                       _Float16* __restrict__ qhi, _Float16* __restrict__ qlo) {
  int w = threadIdx.x >> 6, lane = threadIdx.x & 63;
  int gr = blockIdx.x * 4 + w;  // 0..11967
  int bj = gr / S_N, s = gr - bj * S_N;
  int b = bj >> 3, j = bj & 7;
  float kv[4], qv[4];
#pragma unroll
  for (int q = 0; q < 4; q++) {
    kv[q] = proj[((b * 8 + 2 * q) * S_N + s) * 64 + lane] * g[(b * 8 + 2 * q) * 8 + j];
    qv[q] = proj[((b * 8 + 2 * q + 1) * S_N + s) * 64 + lane] * g[(b * 8 + 2 * q + 1) * 8 + j];
  }
  float mkv = wave_sum(kv[0] + kv[1] + kv[2] + kv[3]) * (1.f / 256.f);
  float mqv = wave_sum(qv[0] + qv[1] + qv[2] + qv[3]) * (1.f / 256.f);
  float vk = 0.f, vq = 0.f;
#pragma unroll
  for (int q = 0; q < 4; q++) {
    float dk = kv[q] - mkv; vk += dk * dk;
    float dq = qv[q] - mqv; vq += dq * dq;
  }
  vk = wave_sum(vk) * (1.f / 256.f);
  vq = wave_sum(vq) * (1.f / 256.f);
  float ik = 1.f / sqrtf(vk + 1e-5f);
  float iq = 1.f / sqrtf(vq + 1e-5f);
  long base = (long)gr * E_N;
#pragma unroll
  for (int q = 0; q < 4; q++) {
    float fk = (kv[q] - mkv) * ik;
    float fq = (qv[q] - mqv) * iq;
    _Float16 hk = (_Float16)fk;
    _Float16 hq = (_Float16)fq;
    khi[base + q * 64 + lane] = hk;
    klo[base + q * 64 + lane] = (_Float16)(fk - (float)hk);
    qhi[base + q * 64 + lane] = hq;
    qlo[base + q * 64 + lane] = (_Float16)(fq - (float)hq);
  }
}

// ---------------- 5. raw = Ktn.Qtn^T via split-f16 MFMA ----------------
// grid = (3 s-tiles, 3 t-tiles, 64 bj); 256 threads = 4 waves
__global__ void k_raw(const _Float16* __restrict__ khi, const _Float16* __restrict__ klo,
                      const _Float16* __restrict__ qhi, const _Float16* __restrict__ qlo,
                      const float* __restrict__ temp, float* __restrict__ w1) {
  int st = blockIdx.x, tt = blockIdx.y, bj = blockIdx.z;
  int wave = threadIdx.x >> 6, lane = threadIdx.x & 63;
  int quad = lane >> 4, m16 = lane & 15;
  int ebase = quad * 8;
  int mrow = st * 64 + wave * 16 + m16;
  if (mrow > S_N - 1) mrow = S_N - 1;
  long aoff = ((long)bj * S_N + mrow) * E_N + ebase;
  const _Float16* ah_p = khi + aoff;
  const _Float16* al_p = klo + aoff;
  const _Float16* bh_p[4];
  const _Float16* bl_p[4];
#pragma unroll
  for (int n = 0; n < 4; n++) {
    int t = tt * 64 + n * 16 + m16;
    if (t > S_N - 1) t = S_N - 1;
    long boff = ((long)bj * S_N + t) * E_N + ebase;
    bh_p[n] = qhi + boff;
    bl_p[n] = qlo + boff;
  }
  floatx4 acc[4] = {};
  for (int ec = 0; ec < 8; ec++) {
    half8 ah = *(const half8*)(ah_p + ec * 32);
    half8 al = *(const half8*)(al_p + ec * 32);
#pragma unroll
    for (int n = 0; n < 4; n++) {
      half8 bh = *(const half8*)(bh_p[n] + ec * 32);
      half8 bl = *(const half8*)(bl_p[n] + ec * 32);
      acc[n] = __builtin_amdgcn_mfma_f32_16x16x32_f16(ah, bh, acc[n], 0, 0, 0);
      acc[n] = __builtin_amdgcn_mfma_f32_16x16x32_f16(al, bh, acc[n], 0, 0, 0);
      acc[n] = __builtin_amdgcn_mfma_f32_16x16x32_f16(ah, bl, acc[n], 0, 0, 0);
    }
  }
  float tv = fabsf(temp[0]) * SQRT_SF + 1e-4f;
  float scale = 1.f / (16.f * tv);
#pragma unroll
  for (int n = 0; n < 4; n++) {
    int t = tt * 64 + n * 16 + m16;  // D col = lane&15
    if (t >= S_N) continue;
#pragma unroll
    for (int r = 0; r < 4; r++) {
      int s = st * 64 + wave * 16 + quad * 4 + r;  // D row = quad*4+reg
      if (s < S_N) w1[((long)bj * S_N + s) * S_N + t] = acc[n][r] * scale;
    }
  }
}

// ---------------- 7. LN(combined)*W2 + b -> x_prime ----------------
__global__ void k_xprime(const float* __restrict__ comb, const float* __restrict__ W2,
                         const float* __restrict__ bparam, const float* __restrict__ lns,
                         const float* __restrict__ lnb, float* __restrict__ xprime) {
  int w = threadIdx.x >> 6, lane = threadIdx.x & 63;
  int gr = blockIdx.x * 4 + w;
  int bj = gr / S_N, s = gr - bj * S_N;
  int j = bj & 7;
  float x = comb[(long)gr * 64 + lane];
  float m = wave_sum(x) * (1.f / 64.f);
  float d = x - m;
  float var = wave_sum(d * d) * (1.f / 64.f);
  float xln = d / sqrtf(var + 1e-5f) * lns[j * 64 + lane] + lnb[j * 64 + lane];
  float acc = bparam[(j * S_N + s) * 64 + lane];
  const float* w2j = W2 + j * 64 * 64;
#pragma unroll 8
  for (int h = 0; h < 64; h++) acc += __shfl(xln, h, 64) * w2j[h * 64 + lane];
  xprime[(long)gr * 64 + lane] = acc;
}

// ---------------- 8. final: softmax + attn apply + conv + residuals ----------------
// grid = (12 s-tiles of 16, 64 bj); 256 threads; wave w owns rows w*4..w*4+3
// (softmax fused here: each wave softmaxes exactly the w1 rows it consumes)
__global__ void k_final(const float* __restrict__ xprime, const float* __restrict__ w1,
                        const float* __restrict__ comb, const float* __restrict__ w3,
                        const float* __restrict__ alpha, const float* __restrict__ beta,
                        const float* __restrict__ theta, const float* __restrict__ gamma,
                        float* __restrict__ out) {
  int tile = blockIdx.x, bj = blockIdx.y;
  int j = bj & 7;
  __shared__ float xp[S_N * 64];     // 47872 B
  __shared__ float w1t[16 * 188];    // 12032 B
  __shared__ float w3l[64 * KS_N];   // 3840 B
  const float4* xpg4 = (const float4*)(xprime + (long)bj * (S_N * 64));
  float4* xp4 = (float4*)xp;
  for (int idx = threadIdx.x; idx < S_N * 16; idx += 256) xp4[idx] = xpg4[idx];
  int s0 = tile * 16;
  for (int idx = threadIdx.x; idx < 16 * S_N; idx += 256) {
    int r = idx / S_N, t = idx - r * S_N;
    int srow = s0 + r;
    w1t[r * 188 + t] = (srow < S_N) ? w1[((long)bj * S_N + srow) * S_N + t] : 0.f;
  }
  for (int idx = threadIdx.x; idx < 64 * KS_N; idx += 256) w3l[idx] = w3[j * 64 * KS_N + idx];
  __syncthreads();
  int w = threadIdx.x >> 6, o = threadIdx.x & 63;
  // --- in-LDS row softmax on this wave's 4 rows (no barrier needed: rows
  // w*4..w*4+3 are consumed only by wave w) ---
#pragma unroll
  for (int rr = 0; rr < 4; rr++) {
    float* row = &w1t[(w * 4 + rr) * 188];
    float v[3];
    float m = -1e30f;
#pragma unroll
    for (int q = 0; q < 3; q++) {
      int t = o + q * 64;
      v[q] = (t < S_N) ? row[t] : -1e30f;
      m = fmaxf(m, v[q]);
    }
    m = wave_max(m);
    float ssum = 0.f;
#pragma unroll
    for (int q = 0; q < 3; q++) {
      int t = o + q * 64;
      float e = (t < S_N) ? expf(v[q] - m) : 0.f;
      v[q] = e;
      ssum += e;
    }
    ssum = wave_sum(ssum);
    float invs = 1.f / ssum;
#pragma unroll
    for (int q = 0; q < 3; q++) {
      int t = o + q * 64;
      if (t < S_N) row[t] = v[q] * invs;
    }
  }
  float aa = fabsf(alpha[j]), ba = fabsf(beta[j]), ta = fabsf(theta[j]), gv = gamma[j];
  float acc[4] = {0.f, 0.f, 0.f, 0.f};
  for (int t = 0; t < 184; t += 4) {
    float x0 = xp[t * 64 + o];
    float x1 = xp[(t + 1) * 64 + o];
    float x2 = xp[(t + 2) * 64 + o];
    float x3 = xp[(t + 3) * 64 + o];
#pragma unroll
    for (int rr = 0; rr < 4; rr++) {
      float4 wv = *(const float4*)&w1t[(w * 4 + rr) * 188 + t];
      acc[rr] += wv.x * x0 + wv.y * x1 + wv.z * x2 + wv.w * x3;
    }
  }
#pragma unroll
  for (int t = 184; t < S_N; t++) {
    float xv = xp[t * 64 + o];
#pragma unroll
    for (int rr = 0; rr < 4; rr++) acc[rr] += w1t[(w * 4 + rr) * 188 + t] * xv;
  }
#pragma unroll
  for (int rr = 0; rr < 4; rr++) {
    int s = s0 + w * 4 + rr;
    if (s >= S_N) continue;
    float conv = 0.f;
#pragma unroll
    for (int k = 0; k < KS_N; k++) {
      int si = s + k - 7;
      if (si >= 0 && si < S_N) conv += xp[si * 64 + o] * w3l[o * KS_N + k];
    }
    float res = ba * acc[rr] + aa * xp[s * 64 + o] + ta * conv +
                gv * comb[((long)bj * S_N + s) * 64 + o];
    out[((long)bj * S_N + s) * 64 + o] = res;
  }
}

extern "C" void kernel_launch(void* const* d_in, const int* in_sizes, int n_in,
                              void* d_out, int out_size, void* d_ws, size_t ws_size,
                              hipStream_t stream) {
  const float* x_in   = (const float*)d_in[0];
  const float* proj   = (const float*)d_in[1];
  const float* sw     = (const float*)d_in[2];
  const float* tau    = (const float*)d_in[3];
  const float* temp   = (const float*)d_in[4];
  const float* omiga  = (const float*)d_in[5];
  const float* W2     = (const float*)d_in[6];
  const float* bparam = (const float*)d_in[7];
  const float* lns    = (const float*)d_in[8];
  const float* lnb    = (const float*)d_in[9];
  const float* alpha  = (const float*)d_in[10];
  const float* beta   = (const float*)d_in[11];
  const float* theta  = (const float*)d_in[12];
  const float* gamma  = (const float*)d_in[13];
  const float* w3     = (const float*)d_in[14];

  float* out = (float*)d_out;
  float* xprime = out + B_N * J_N * S_N * O_N;  // second output, written directly

  float* wsf = (float*)d_ws;
  unsigned int* maxb = (unsigned int*)d_ws;       // wsf[0]
  float* esum  = wsf + 64;                        // 512 floats
  float* maskv = wsf + 640;                       // 512 floats
  float* g     = wsf + 1152;                      // 512 floats
  const long RE = (long)ROWS_N * E_N;             // 3,063,808 halves per array
  _Float16* khi = (_Float16*)(wsf + 2048);
  _Float16* klo = khi + RE;
  _Float16* qhi = klo + RE;
  _Float16* qlo = qhi + RE;
  float* w1   = wsf + 2048 + 2 * RE;
  float* comb = w1 + (long)B_N * J_N * S_N * S_N;

  hipMemsetAsync(d_ws, 0, 2304, stream);
  k_maxabs<<<64, 256, 0, stream>>>((const float4*)x_in, maxb, (B_N * IN_N * S_N * F_N) / 4);
  k_energy_part<<<B_N * IN_N * 4, 256, 0, stream>>>(x_in, sw, omiga, maxb, esum);
  k_energy_fin<<<1, 512, 0, stream>>>(esum, tau, temp, maskv, g);
  k_combined<<<dim3((SF_N + 255) / 256, B_N), 256, 0, stream>>>(x_in, sw, omiga, maxb, maskv, comb);
  k_ktqt<<<ROWS_N / 4, 256, 0, stream>>>(proj, g, khi, klo, qhi, qlo);
  k_raw<<<dim3(3, 3, 64), 256, 0, stream>>>(khi, klo, qhi, qlo, temp, w1);
  k_xprime<<<ROWS_N / 4, 256, 0, stream>>>(comb, W2, bparam, lns, lnb, xprime);
  k_final<<<dim3(12, 64), 256, 0, stream>>>(xprime, w1, comb, w3, alpha, beta, theta, gamma, out);
}